// Round 18
// baseline (74.054 us; speedup 1.0000x reference)
//
#include <hip/hip_runtime.h>
#include <hip/hip_bf16.h>

typedef __attribute__((ext_vector_type(8))) short short8;
typedef __attribute__((ext_vector_type(4))) float f32x4;
typedef __attribute__((ext_vector_type(2))) unsigned uint2v;

#define MFMA16(a, b, c) __builtin_amdgcn_mfma_f32_16x16x32_bf16((a), (b), (c), 0, 0, 0)

constexpr int Bc = 2, Lc = 2048, Hc = 16, Ec = 64;
constexpr float LOG2E = 1.4426950408889634f;
constexpr float SCALE2 = 0.125f * LOG2E;   // fold log2(e): scores in log2 units
constexpr float NEGBIG = -3.0e38f;

union SW { short8 s8; unsigned u[4]; float4 f4; };

__device__ __forceinline__ unsigned cvtpk(float lo, float hi) {
  unsigned r;
  asm("v_cvt_pk_bf16_f32 %0, %1, %2" : "=v"(r) : "v"(lo), "v"(hi));
  return r;
}
__device__ __forceinline__ float exp2v(float x) {
  float r;
  asm("v_exp_f32 %0, %1" : "=v"(r) : "v"(x));
  return r;
}
__device__ __forceinline__ void plswap32(unsigned& a, unsigned& b) {
  uint2v r = __builtin_amdgcn_permlane32_swap(a, b, false, false);
  a = r[0]; b = r[1];
}
__device__ __forceinline__ void plswap16(unsigned& a, unsigned& b) {
  uint2v r = __builtin_amdgcn_permlane16_swap(a, b, false, false);
  a = r[0]; b = r[1];
}
__device__ __forceinline__ float bflymax(float x) {
  unsigned a = __builtin_bit_cast(unsigned, x), b = a;
  plswap16(a, b);
  float y = fmaxf(__builtin_bit_cast(float, a), __builtin_bit_cast(float, b));
  a = __builtin_bit_cast(unsigned, y); b = a;
  plswap32(a, b);
  return fmaxf(__builtin_bit_cast(float, a), __builtin_bit_cast(float, b));
}

// Fused prepass (unchanged from r17): K fp32->bf16; V -> chunk-major
// Vt[bh][s/16][e][16] bf16, reads and writes coalesced.
__global__ __launch_bounds__(256)
void prep(const float* __restrict__ K, const float* __restrict__ V,
          uint4* __restrict__ Kb, unsigned short* __restrict__ Vt) {
  const int bid = blockIdx.x;
  const int t = threadIdx.x;
  if (bid < 2048) {
    const int i = bid * 256 + t;
    const float4* s = reinterpret_cast<const float4*>(K) + (size_t)i * 2;
    float4 a = s[0], b = s[1];
    uint4 o;
    o.x = cvtpk(a.x, a.y); o.y = cvtpk(a.z, a.w);
    o.z = cvtpk(b.x, b.y); o.w = cvtpk(b.z, b.w);
    Kb[i] = o;
  } else {
    const int vw = (bid - 2048) * 4 + (t >> 6);   // bh*128 + chunk
    const int l = t & 63;                          // e
    const int bh = vw >> 7;
    const int s0 = (vw & 127) * 16;
    const float* vp = V + ((size_t)(bh >> 4) * Lc + s0) * (Hc * Ec) +
                      (bh & 15) * Ec + l;
    float va[16];
    #pragma unroll
    for (int j = 0; j < 16; ++j) va[j] = vp[j * (Hc * Ec)];
    uint4 o0, o1;
    o0.x = cvtpk(va[0], va[1]);   o0.y = cvtpk(va[2], va[3]);
    o0.z = cvtpk(va[4], va[5]);   o0.w = cvtpk(va[6], va[7]);
    o1.x = cvtpk(va[8], va[9]);   o1.y = cvtpk(va[10], va[11]);
    o1.z = cvtpk(va[12], va[13]); o1.w = cvtpk(va[14], va[15]);
    uint4* dst = reinterpret_cast<uint4*>(Vt + ((size_t)vw * 64 + l) * 16);
    dst[0] = o0;
    dst[1] = o1;
  }
}

__global__ __launch_bounds__(512, 2)
void attn_fwd(const float* __restrict__ Qg, const unsigned short* __restrict__ Kb,
              const unsigned short* __restrict__ Vt, float* __restrict__ Og) {
  // smem (shorts), NT=128 dbuf: kt[b] at b*8192, vt[b] at 16384+b*8192.
  // Merge scratch overlays the retired buffer (fp32, XOR-swizzled e-offset).
  __shared__ __align__(16) short smem[32768];
  __shared__ float mls[2][64], lls[2][64];

  const int bid = blockIdx.x;
  const int pair = bid & 15;
  const int bh = bid >> 4;
  const int h = bh & (Hc - 1);
  const int b = bh >> 4;
  const int iLo = pair;
  const int QbL = iLo * 64;
  const int QbH = (31 - pair) * 64;
  const int RL = (iLo + 2) >> 1;              // lo-tile rounds; RL + RH = 17

  const int t = threadIdx.x;
  const int w = t >> 6;         // 0..7
  const int qsubg = w & 1;      // 32-q group
  const int spar = w >> 1;      // s-quarter 0..3 (32 s each)
  const int l = t & 63;
  const int n = l & 15;
  const int g = l >> 4;
  const int sp4 = ((g & 1) << 3) | ((g >> 1) << 2);  // pi(g)*4

  const f32x4 zero4 = {0.f, 0.f, 0.f, 0.f};
  short8 onesv;
  #pragma unroll
  for (int j = 0; j < 8; ++j) onesv[j] = (short)0x3F80;  // bf16 1.0

  // Q fragments: two 16-q sub-tiles per wave (B-operand: col=q, k=e)
  short8 qf[2][2];
  auto loadq = [&](int Qb) {
    #pragma unroll
    for (int qi = 0; qi < 2; ++qi) {
      const int q = Qb + qsubg * 32 + qi * 16 + n;
      const float* qp = Qg + ((size_t)(b * Lc + q) * Hc + h) * Ec + g * 8;
      SW a0, a1, b0, b1, r0, r1;
      a0.f4 = reinterpret_cast<const float4*>(qp)[0];
      a1.f4 = reinterpret_cast<const float4*>(qp)[1];
      b0.f4 = reinterpret_cast<const float4*>(qp + 32)[0];
      b1.f4 = reinterpret_cast<const float4*>(qp + 32)[1];
      r0.u[0] = cvtpk(a0.f4.x * SCALE2, a0.f4.y * SCALE2);
      r0.u[1] = cvtpk(a0.f4.z * SCALE2, a0.f4.w * SCALE2);
      r0.u[2] = cvtpk(a1.f4.x * SCALE2, a1.f4.y * SCALE2);
      r0.u[3] = cvtpk(a1.f4.z * SCALE2, a1.f4.w * SCALE2);
      r1.u[0] = cvtpk(b0.f4.x * SCALE2, b0.f4.y * SCALE2);
      r1.u[1] = cvtpk(b0.f4.z * SCALE2, b0.f4.w * SCALE2);
      r1.u[2] = cvtpk(b1.f4.x * SCALE2, b1.f4.y * SCALE2);
      r1.u[3] = cvtpk(b1.f4.z * SCALE2, b1.f4.w * SCALE2);
      qf[qi][0] = r0.s8;
      qf[qi][1] = r1.s8;
    }
  };

  // acc[qi][e4][r] = O^T[e][q=n] for q-sub-tile qi; per-lane scalar m,l per qi
  f32x4 acc[2][4] = {{zero4, zero4, zero4, zero4}, {zero4, zero4, zero4, zero4}};
  float mrun[2] = {NEGBIG, NEGBIG}, lrun[2] = {0.f, 0.f};

  // staging (by thread, role-independent): 128 K rows + 128 V^T chunk-rows
  const int srow = t >> 2;
  const int prow = (srow & ~12) | ((srow & 4) << 1) | ((srow & 8) >> 1);
  const int kc0 = (t & 3) * 16;
  const int ve = l, vs0 = w * 16;

  float4 kA, kB, vA, vB;

  auto issue = [&](int r0) {
    unsigned koff = (unsigned)((((b * Lc + r0 + srow) * Hc + h) * Ec + kc0) * 2);
    unsigned voff = (unsigned)(((bh * 128 + ((r0 + vs0) >> 4)) * 64 + ve) * 32);
    asm volatile(
      "global_load_dwordx4 %[k0], %[ko], %[kb]\n\t"
      "global_load_dwordx4 %[k1], %[ko], %[kb] offset:16\n\t"
      "global_load_dwordx4 %[v0], %[vo], %[vb]\n\t"
      "global_load_dwordx4 %[v1], %[vo], %[vb] offset:16"
      : [k0]"=v"(kA), [k1]"=v"(kB), [v0]"=v"(vA), [v1]"=v"(vB)
      : [ko]"v"(koff), [vo]"v"(voff), [kb]"s"(Kb), [vb]"s"(Vt)
      : "memory");
  };
  auto commit = [&](int buf) {
    asm volatile("s_waitcnt vmcnt(2)" ::: "memory");
    __builtin_amdgcn_sched_barrier(0);
    short* kt = smem + buf * 8192;
    *reinterpret_cast<short8*>(&kt[(prow * 64 + kc0) ^ ((prow & 7) << 3)]) =
        *reinterpret_cast<short8*>(&kA);
    *reinterpret_cast<short8*>(&kt[(prow * 64 + kc0 + 8) ^ ((prow & 7) << 3)]) =
        *reinterpret_cast<short8*>(&kB);
    asm volatile("s_waitcnt vmcnt(0)" ::: "memory");
    __builtin_amdgcn_sched_barrier(0);
    short* vt = smem + 16384 + buf * 8192;
    const int ch0 = vs0 >> 3;
    *reinterpret_cast<short8*>(&vt[ve * 128 + (((ch0 + 0) ^ (ve & 7)) << 3)]) =
        *reinterpret_cast<short8*>(&vA);
    *reinterpret_cast<short8*>(&vt[ve * 128 + (((ch0 + 1) ^ (ve & 7)) << 3)]) =
        *reinterpret_cast<short8*>(&vB);
  };

  // softmax for one 16-q sub-tile over this wave's 32 s (mask, max, rescale,
  // exp, pack, permlane-relayout, ones-MFMA row sum). Returns the P B-frag.
  auto smx = [&](f32x4 (&S)[2], f32x4 (&A)[4], float& M, float& L,
                 int qtop, int sb) -> SW {
    if (sb + 31 > qtop) {
      #pragma unroll
      for (int cb = 0; cb < 2; ++cb)
        #pragma unroll
        for (int r = 0; r < 4; ++r)
          if (sb + cb * 16 + sp4 + r > qtop + n) S[cb][r] = NEGBIG;
    }
    float m8 = fmaxf(fmaxf(fmaxf(S[0][0], S[0][1]), fmaxf(S[0][2], S[0][3])),
                     fmaxf(fmaxf(S[1][0], S[1][1]), fmaxf(S[1][2], S[1][3])));
    m8 = bflymax(m8);
    const bool resc = !__all(m8 <= M);
    if (resc) {
      const float mn = fmaxf(M, m8);
      const float af = exp2v(M - mn);
      M = mn;
      L *= af;
      #pragma unroll
      for (int e4 = 0; e4 < 4; ++e4)
        #pragma unroll
        for (int r = 0; r < 4; ++r) A[e4][r] *= af;
    }
    unsigned ua0 = cvtpk(exp2v(S[0][0] - M), exp2v(S[0][1] - M));
    unsigned ub0 = cvtpk(exp2v(S[0][2] - M), exp2v(S[0][3] - M));
    unsigned ua1 = cvtpk(exp2v(S[1][0] - M), exp2v(S[1][1] - M));
    unsigned ub1 = cvtpk(exp2v(S[1][2] - M), exp2v(S[1][3] - M));
    plswap32(ua0, ua1);
    plswap32(ub0, ub1);
    SW pw;
    pw.u[0] = ua0; pw.u[1] = ub0; pw.u[2] = ua1; pw.u[3] = ub1;
    f32x4 rs = MFMA16(onesv, pw.s8, zero4);
    L += rs[0];
    return pw;
  };

  // one 64q x 128s round; this wave: 32 q x 32 s; kf/vf shared across 2 q-tiles
  auto round = [&](int Qb, int str, int curb) {
    const int sb = str * 128 + spar * 32;
    const int qtopg = Qb + qsubg * 32;
    if (sb > qtopg + 31) return;
    const bool act0 = (sb <= qtopg + 15);
    const short* ktb = smem + curb * 8192;
    const short* vtb = smem + 16384 + curb * 8192;

    f32x4 sc[2][2] = {{zero4, zero4}, {zero4, zero4}};
    #pragma unroll
    for (int kc = 0; kc < 2; ++kc) {
      #pragma unroll
      for (int cb = 0; cb < 2; ++cb) {
        const int row = spar * 32 + cb * 16 + n;
        const int idx = (row * 64 + kc * 32 + g * 8) ^ ((n & 7) << 3);
        short8 kf = *reinterpret_cast<const short8*>(&ktb[idx]);
        sc[1][cb] = MFMA16(kf, qf[1][kc], sc[1][cb]);
        if (act0) sc[0][cb] = MFMA16(kf, qf[0][kc], sc[0][cb]);
      }
    }

    SW pw1 = smx(sc[1], acc[1], mrun[1], lrun[1], qtopg + 16, sb);
    SW pw0{};
    if (act0) pw0 = smx(sc[0], acc[0], mrun[0], lrun[0], qtopg, sb);

    #pragma unroll
    for (int e4 = 0; e4 < 4; ++e4) {
      const int e = e4 * 16 + n;
      const int slot = (spar * 4 + g) ^ (e & 7);
      short8 vf = *reinterpret_cast<const short8*>(&vtb[e * 128 + (slot << 3)]);
      acc[1][e4] = MFMA16(vf, pw1.s8, acc[1][e4]);
      if (act0) acc[0][e4] = MFMA16(vf, pw0.s8, acc[0][e4]);
    }
  };

  // ---- 4-way merge via retired buffer (pairwise tree, swizzled fp32) ----
  auto wpart = [&](float* reg, int mreg) {
    #pragma unroll
    for (int qi = 0; qi < 2; ++qi) {
      const int row = qsubg * 32 + qi * 16 + n;
      #pragma unroll
      for (int e4 = 0; e4 < 4; ++e4) {
        const int eo = (e4 * 16 + g * 4) ^ ((n & 7) << 2);
        float4 v;
        v.x = acc[qi][e4][0]; v.y = acc[qi][e4][1];
        v.z = acc[qi][e4][2]; v.w = acc[qi][e4][3];
        *reinterpret_cast<float4*>(&reg[row * 64 + eo]) = v;
      }
      if (g == 0) { mls[mreg][row] = mrun[qi]; lls[mreg][row] = lrun[qi]; }
    }
  };
  auto mpart = [&](const float* reg, int mreg) {
    #pragma unroll
    for (int qi = 0; qi < 2; ++qi) {
      const int row = qsubg * 32 + qi * 16 + n;
      const float m1 = mls[mreg][row];
      const float l1 = lls[mreg][row];
      const float mm = fmaxf(mrun[qi], m1);
      const float a0 = exp2v(mrun[qi] - mm);
      const float a1 = exp2v(m1 - mm);
      mrun[qi] = mm;
      lrun[qi] = lrun[qi] * a0 + l1 * a1;
      #pragma unroll
      for (int e4 = 0; e4 < 4; ++e4) {
        const int eo = (e4 * 16 + g * 4) ^ ((n & 7) << 2);
        float4 pv = *reinterpret_cast<const float4*>(&reg[row * 64 + eo]);
        acc[qi][e4][0] = acc[qi][e4][0] * a0 + pv.x * a1;
        acc[qi][e4][1] = acc[qi][e4][1] * a0 + pv.y * a1;
        acc[qi][e4][2] = acc[qi][e4][2] * a0 + pv.z * a1;
        acc[qi][e4][3] = acc[qi][e4][3] * a0 + pv.w * a1;
      }
    }
  };
  auto merge_store = [&](int Qb, int curb) {
    float* regA = reinterpret_cast<float*>(smem + curb * 8192);
    float* regB = reinterpret_cast<float*>(smem + 16384 + curb * 8192);
    __syncthreads();
    if (spar == 1) wpart(regA, 0);
    if (spar == 3) wpart(regB, 1);
    __syncthreads();
    if (spar == 0) mpart(regA, 0);
    if (spar == 2) mpart(regB, 1);
    __syncthreads();
    if (spar == 2) wpart(regA, 0);
    __syncthreads();
    if (spar == 0) {
      mpart(regA, 0);
      #pragma unroll
      for (int qi = 0; qi < 2; ++qi) {
        const float inv = 1.0f / lrun[qi];
        const int row = qsubg * 32 + qi * 16 + n;
        const int q = Qb + row;
        float* op = Og + ((size_t)(b * Lc + q) * Hc + h) * Ec;
        #pragma unroll
        for (int e4 = 0; e4 < 4; ++e4) {
          float4 v;
          v.x = acc[qi][e4][0] * inv;
          v.y = acc[qi][e4][1] * inv;
          v.z = acc[qi][e4][2] * inv;
          v.w = acc[qi][e4][3] * inv;
          *reinterpret_cast<float4*>(op + e4 * 16 + g * 4) = v;
        }
      }
    }
  };

  // fused 17-round stream: rounds 0..RL-1 on tile lo, rest on tile hi
  constexpr int NRO = 17;
  loadq(QbL);
  issue(0);
  commit(0);
  __syncthreads();

  int cur = 0;
  for (int rd = 0; rd < NRO; ++rd) {
    const bool pre = (rd + 1 < NRO);
    if (pre) {
      const int nrd = rd + 1;
      const int nstr = (nrd < RL) ? nrd : nrd - RL;
      issue(nstr * 128);
    }
    const bool lo = (rd < RL);
    round(lo ? QbL : QbH, lo ? rd : rd - RL, cur);
    if (rd == RL - 1) {
      merge_store(QbL, cur);   // scratch overlays the just-consumed buffer
      #pragma unroll
      for (int qi = 0; qi < 2; ++qi) {
        #pragma unroll
        for (int e4 = 0; e4 < 4; ++e4) acc[qi][e4] = zero4;
        mrun[qi] = NEGBIG;
        lrun[qi] = 0.f;
      }
      loadq(QbH);
    }
    if (pre) commit(cur ^ 1);
    __syncthreads();
    cur ^= 1;
  }

  merge_store(QbH, cur ^ 1);
}

extern "C" void kernel_launch(void* const* d_in, const int* in_sizes, int n_in,
                              void* d_out, int out_size, void* d_ws, size_t ws_size,
                              hipStream_t stream) {
  const float* Q = (const float*)d_in[0];
  const float* K = (const float*)d_in[1];
  const float* V = (const float*)d_in[2];
  float* O = (float*)d_out;
  unsigned short* Kb = (unsigned short*)d_ws;
  unsigned short* Vt = (unsigned short*)((char*)d_ws + (size_t)Bc * Lc * Hc * Ec * 2);
  prep<<<dim3(3072), dim3(256), 0, stream>>>(K, V, (uint4*)Kb, Vt);
  dim3 grid(Bc * Hc * 16);   // 32 bh x 16 folded pairs, all identical work
  attn_fwd<<<grid, dim3(512), 0, stream>>>(Q, Kb, Vt, O);
}

// Round 19
// 49.529 us; speedup vs baseline: 1.4952x; 1.4952x over previous
//
#include <hip/hip_runtime.h>
#include <hip/hip_bf16.h>

typedef __attribute__((ext_vector_type(8))) short short8;
typedef __attribute__((ext_vector_type(4))) float f32x4;
typedef __attribute__((ext_vector_type(2))) unsigned uint2v;

#define MFMA16(a, b, c) __builtin_amdgcn_mfma_f32_16x16x32_bf16((a), (b), (c), 0, 0, 0)

constexpr int Bc = 2, Lc = 2048, Hc = 16, Ec = 64;
constexpr float LOG2E = 1.4426950408889634f;
constexpr float SCALE2 = 0.125f * LOG2E;   // fold log2(e): scores in log2 units
constexpr float NEGBIG = -3.0e38f;

union SW { short8 s8; unsigned u[4]; float4 f4; };

__device__ __forceinline__ unsigned cvtpk(float lo, float hi) {
  unsigned r;
  asm("v_cvt_pk_bf16_f32 %0, %1, %2" : "=v"(r) : "v"(lo), "v"(hi));
  return r;
}
__device__ __forceinline__ float exp2v(float x) {
  float r;
  asm("v_exp_f32 %0, %1" : "=v"(r) : "v"(x));
  return r;
}
__device__ __forceinline__ void plswap32(unsigned& a, unsigned& b) {
  uint2v r = __builtin_amdgcn_permlane32_swap(a, b, false, false);
  a = r[0]; b = r[1];
}
__device__ __forceinline__ void plswap16(unsigned& a, unsigned& b) {
  uint2v r = __builtin_amdgcn_permlane16_swap(a, b, false, false);
  a = r[0]; b = r[1];
}
__device__ __forceinline__ float bflymax(float x) {
  unsigned a = __builtin_bit_cast(unsigned, x), b = a;
  plswap16(a, b);
  float y = fmaxf(__builtin_bit_cast(float, a), __builtin_bit_cast(float, b));
  a = __builtin_bit_cast(unsigned, y); b = a;
  plswap32(a, b);
  return fmaxf(__builtin_bit_cast(float, a), __builtin_bit_cast(float, b));
}

// Fused prepass: K fp32->bf16 (RNE); V -> chunk-major Vt[bh][s/16][e][16] bf16.
__global__ __launch_bounds__(256)
void prep(const float* __restrict__ K, const float* __restrict__ V,
          uint4* __restrict__ Kb, unsigned short* __restrict__ Vt) {
  const int bid = blockIdx.x;
  const int t = threadIdx.x;
  if (bid < 2048) {
    const int i = bid * 256 + t;
    const float4* s = reinterpret_cast<const float4*>(K) + (size_t)i * 2;
    float4 a = s[0], b = s[1];
    uint4 o;
    o.x = cvtpk(a.x, a.y); o.y = cvtpk(a.z, a.w);
    o.z = cvtpk(b.x, b.y); o.w = cvtpk(b.z, b.w);
    Kb[i] = o;
  } else {
    const int vw = (bid - 2048) * 4 + (t >> 6);   // bh*128 + chunk
    const int l = t & 63;                          // e
    const int bh = vw >> 7;
    const int s0 = (vw & 127) * 16;
    const float* vp = V + ((size_t)(bh >> 4) * Lc + s0) * (Hc * Ec) +
                      (bh & 15) * Ec + l;
    float va[16];
    #pragma unroll
    for (int j = 0; j < 16; ++j) va[j] = vp[j * (Hc * Ec)];
    uint4 o0, o1;
    o0.x = cvtpk(va[0], va[1]);   o0.y = cvtpk(va[2], va[3]);
    o0.z = cvtpk(va[4], va[5]);   o0.w = cvtpk(va[6], va[7]);
    o1.x = cvtpk(va[8], va[9]);   o1.y = cvtpk(va[10], va[11]);
    o1.z = cvtpk(va[12], va[13]); o1.w = cvtpk(va[14], va[15]);
    uint4* dst = reinterpret_cast<uint4*>(Vt + ((size_t)vw * 64 + l) * 16);
    dst[0] = o0;
    dst[1] = o1;
  }
}

__global__ __launch_bounds__(512, 2)
void attn_fwd(const float* __restrict__ Qg, const unsigned short* __restrict__ Kb,
              const unsigned short* __restrict__ Vt, float* __restrict__ Og) {
  // smem (shorts), NT=128 s-tile double-buffered:
  //  kt[b]: [128][64] bf16 at b*8192, K row s at prow=pi(s), idx ^ ((prow&7)<<3)
  //  vt[b]: [64 e][128 s] bf16 at 16384 + b*8192, chunk slot = (s>>3) ^ (e&7)
  // merge scratch overlays the RETIRED buffer.
  __shared__ __align__(16) short smem[32768];

  // XCD-locality decode: bid = pair*32 + bh -> all 16 pair-blocks of a bh
  // share bid mod 8 (same XCD L2); the 2 blocks/CU share the same bh (same
  // 2MB KV working set). All blocks run exactly 17 uniform rounds.
  const int bid = blockIdx.x;
  const int pair = bid >> 5;
  const int bh = bid & 31;
  const int h = bh & (Hc - 1);
  const int b = bh >> 4;
  const int iLo = pair;
  const int QbL = iLo * 64;
  const int QbH = (31 - pair) * 64;
  const int RL = (iLo + 2) >> 1;              // lo-tile rounds; RL + RH = 17

  const int t = threadIdx.x;
  const int w = t >> 6;        // 0..7
  const int qsub = w & 3;      // q sub-block (16 rows)
  const int par = w >> 2;      // 64-s half of the 128-row tile
  const int l = t & 63;
  const int n = l & 15;
  const int g = l >> 4;
  const int sp4 = ((g & 1) << 3) | ((g >> 1) << 2);  // pi(g)*4

  const f32x4 zero4 = {0.f, 0.f, 0.f, 0.f};
  short8 onesv;
  #pragma unroll
  for (int j = 0; j < 8; ++j) onesv[j] = (short)0x3F80;  // bf16 1.0

  // Q fragments (B-operand: col=q=lane&15, k=e=(lane>>4)*8+j)
  short8 qf[2];
  auto loadq = [&](int Qb) {
    const int q = Qb + qsub * 16 + n;
    const float* qp = Qg + ((size_t)(b * Lc + q) * Hc + h) * Ec + g * 8;
    SW a0, a1, b0, b1, r0, r1;
    a0.f4 = reinterpret_cast<const float4*>(qp)[0];
    a1.f4 = reinterpret_cast<const float4*>(qp)[1];
    b0.f4 = reinterpret_cast<const float4*>(qp + 32)[0];
    b1.f4 = reinterpret_cast<const float4*>(qp + 32)[1];
    r0.u[0] = cvtpk(a0.f4.x * SCALE2, a0.f4.y * SCALE2);
    r0.u[1] = cvtpk(a0.f4.z * SCALE2, a0.f4.w * SCALE2);
    r0.u[2] = cvtpk(a1.f4.x * SCALE2, a1.f4.y * SCALE2);
    r0.u[3] = cvtpk(a1.f4.z * SCALE2, a1.f4.w * SCALE2);
    r1.u[0] = cvtpk(b0.f4.x * SCALE2, b0.f4.y * SCALE2);
    r1.u[1] = cvtpk(b0.f4.z * SCALE2, b0.f4.w * SCALE2);
    r1.u[2] = cvtpk(b1.f4.x * SCALE2, b1.f4.y * SCALE2);
    r1.u[3] = cvtpk(b1.f4.z * SCALE2, b1.f4.w * SCALE2);
    qf[0] = r0.s8;
    qf[1] = r1.s8;
  };

  // acc[e4][r] = O^T[e = e4*16 + g*4 + r][q = n]; per-lane scalar m,l
  f32x4 acc[4] = {zero4, zero4, zero4, zero4};
  float mrun = NEGBIG, lrun = 0.f;

  // staging: 512 threads stage 128 rows of K (pi-permuted) and V^T per round
  const int srow = t >> 2;                               // 0..127
  const int prow = (srow & ~12) | ((srow & 4) << 1) | ((srow & 8) >> 1);
  const int kc0 = (t & 3) * 16;                          // 16-col bf16 chunk
  const int ve = l, vs0 = w * 16;                        // V^T: e=lane, 16 s rows

  float4 kA, kB, vA, vB;   // 4 x dwordx4 bf16

  // Forced-async bf16 stage: volatile asm loads issue HERE (unsinkable).
  auto issue = [&](int r0) {
    unsigned koff = (unsigned)((((b * Lc + r0 + srow) * Hc + h) * Ec + kc0) * 2);
    unsigned voff = (unsigned)(((bh * 128 + ((r0 + vs0) >> 4)) * 64 + ve) * 32);
    asm volatile(
      "global_load_dwordx4 %[k0], %[ko], %[kb]\n\t"
      "global_load_dwordx4 %[k1], %[ko], %[kb] offset:16\n\t"
      "global_load_dwordx4 %[v0], %[vo], %[vb]\n\t"
      "global_load_dwordx4 %[v1], %[vo], %[vb] offset:16"
      : [k0]"=v"(kA), [k1]"=v"(kB), [v0]"=v"(vA), [v1]"=v"(vB)
      : [ko]"v"(koff), [vo]"v"(voff), [kb]"s"(Kb), [vb]"s"(Vt)
      : "memory");
  };
  auto commit = [&](int buf) {
    asm volatile("s_waitcnt vmcnt(2)" ::: "memory");
    __builtin_amdgcn_sched_barrier(0);
    short* kt = smem + buf * 8192;
    *reinterpret_cast<short8*>(&kt[(prow * 64 + kc0) ^ ((prow & 7) << 3)]) =
        *reinterpret_cast<short8*>(&kA);
    *reinterpret_cast<short8*>(&kt[(prow * 64 + kc0 + 8) ^ ((prow & 7) << 3)]) =
        *reinterpret_cast<short8*>(&kB);
    asm volatile("s_waitcnt vmcnt(0)" ::: "memory");
    __builtin_amdgcn_sched_barrier(0);
    short* vt = smem + 16384 + buf * 8192;
    const int ch0 = vs0 >> 3;
    *reinterpret_cast<short8*>(&vt[ve * 128 + (((ch0 + 0) ^ (ve & 7)) << 3)]) =
        *reinterpret_cast<short8*>(&vA);
    *reinterpret_cast<short8*>(&vt[ve * 128 + (((ch0 + 1) ^ (ve & 7)) << 3)]) =
        *reinterpret_cast<short8*>(&vB);
  };

  // one 64q x 128s round (this wave: 16 q x 64 s half), swapped operands
  auto round = [&](int Qb, int str, int curb) {
    const int sb = str * 128 + par * 64;
    const int qtop = Qb + qsub * 16;
    if (sb > qtop + 15) return;
    const short* ktb = smem + curb * 8192;
    const short* vtb = smem + 16384 + curb * 8192;

    // QK^T swapped: D[s][q], col = q = n; 4 cb blocks x k=64
    f32x4 sc[4] = {zero4, zero4, zero4, zero4};
    #pragma unroll
    for (int kc = 0; kc < 2; ++kc) {
      #pragma unroll
      for (int cb = 0; cb < 4; ++cb) {
        const int row = par * 64 + cb * 16 + n;
        const int idx = (row * 64 + kc * 32 + g * 8) ^ ((n & 7) << 3);
        short8 kf = *reinterpret_cast<const short8*>(&ktb[idx]);
        sc[cb] = MFMA16(kf, qf[kc], sc[cb]);
      }
    }

    const int qg = qtop + n;
    if (sb + 63 > qtop) {
      #pragma unroll
      for (int cb = 0; cb < 4; ++cb)
        #pragma unroll
        for (int r = 0; r < 4; ++r)
          if (sb + cb * 16 + sp4 + r > qg) sc[cb][r] = NEGBIG;
    }

    // row max: 15 lane-local fmax + VALU butterfly
    float m8 = fmaxf(fmaxf(fmaxf(sc[0][0], sc[0][1]), fmaxf(sc[0][2], sc[0][3])),
                     fmaxf(fmaxf(sc[1][0], sc[1][1]), fmaxf(sc[1][2], sc[1][3])));
    m8 = fmaxf(m8, fmaxf(fmaxf(fmaxf(sc[2][0], sc[2][1]), fmaxf(sc[2][2], sc[2][3])),
                         fmaxf(fmaxf(sc[3][0], sc[3][1]), fmaxf(sc[3][2], sc[3][3]))));
    m8 = bflymax(m8);

    // exact-identity rescale skip
    const bool resc = !__all(m8 <= mrun);
    if (resc) {
      const float mn = fmaxf(mrun, m8);
      const float afac = exp2v(mrun - mn);
      mrun = mn;
      lrun *= afac;
      #pragma unroll
      for (int e4 = 0; e4 < 4; ++e4)
        #pragma unroll
        for (int r = 0; r < 4; ++r) acc[e4][r] *= afac;
    }

    // P = exp2(S - m) -> packed bf16
    unsigned ua[4], ub[4];
    #pragma unroll
    for (int cb = 0; cb < 4; ++cb) {
      ua[cb] = cvtpk(exp2v(sc[cb][0] - mrun), exp2v(sc[cb][1] - mrun));
      ub[cb] = cvtpk(exp2v(sc[cb][2] - mrun), exp2v(sc[cb][3] - mrun));
    }

    // P C-frag -> B-frag: pure-VALU permlane32 swaps
    plswap32(ua[0], ua[1]);
    plswap32(ub[0], ub[1]);
    plswap32(ua[2], ua[3]);
    plswap32(ub[2], ub[3]);
    SW pw0, pw1;
    pw0.u[0] = ua[0]; pw0.u[1] = ub[0]; pw0.u[2] = ua[1]; pw0.u[3] = ub[1];
    pw1.u[0] = ua[2]; pw1.u[1] = ub[2]; pw1.u[2] = ua[3]; pw1.u[3] = ub[3];

    // PV swapped: acc = V^T x P, two k=32 slices per e-chunk
    #pragma unroll
    for (int e4 = 0; e4 < 4; ++e4) {
      const int e = e4 * 16 + n;
      const int slot0 = (par * 8 + g) ^ (e & 7);
      const int slot1 = (par * 8 + 4 + g) ^ (e & 7);
      short8 vf0 = *reinterpret_cast<const short8*>(&vtb[e * 128 + (slot0 << 3)]);
      acc[e4] = MFMA16(vf0, pw0.s8, acc[e4]);
      short8 vf1 = *reinterpret_cast<const short8*>(&vtb[e * 128 + (slot1 << 3)]);
      acc[e4] = MFMA16(vf1, pw1.s8, acc[e4]);
    }

    // row sum via ones-MFMA: D[i][q] = sum_s P[s][q], lane col q = n
    f32x4 rs = MFMA16(onesv, pw0.s8, zero4);
    rs = MFMA16(onesv, pw1.s8, rs);
    lrun += rs[0];
  };

  // merge parities via scratch overlaid on the retired buffer `curb`
  auto merge_store = [&](int Qb, int curb) {
    float* sA = reinterpret_cast<float*>(smem) + curb * 4096;         // rows 0..31
    float* sB = reinterpret_cast<float*>(smem) + 8192 + curb * 4096;  // rows 32..63 + m + l
    __syncthreads();
    const int row = qsub * 16 + n;
    if (par == 1) {
      float* base = (row < 32) ? (sA + row * 68) : (sB + (row - 32) * 68);
      #pragma unroll
      for (int e4 = 0; e4 < 4; ++e4)
        #pragma unroll
        for (int r = 0; r < 4; ++r) base[e4 * 16 + g * 4 + r] = acc[e4][r];
      if (g == 0) {
        sB[2176 + row] = mrun;
        sB[2240 + row] = lrun;
      }
    }
    __syncthreads();
    if (par == 0) {
      const float* base = (row < 32) ? (sA + row * 68) : (sB + (row - 32) * 68);
      const float m1 = sB[2176 + row];
      const float l1 = sB[2240 + row];
      const float mm = fmaxf(mrun, m1);
      const float a0 = exp2v(mrun - mm);
      const float a1 = exp2v(m1 - mm);
      const float inv = 1.0f / (lrun * a0 + l1 * a1);
      const int q = Qb + row;
      float* op = Og + ((size_t)(b * Lc + q) * Hc + h) * Ec;
      #pragma unroll
      for (int e4 = 0; e4 < 4; ++e4) {
        float4 v;
        v.x = (acc[e4][0] * a0 + base[e4 * 16 + g * 4 + 0] * a1) * inv;
        v.y = (acc[e4][1] * a0 + base[e4 * 16 + g * 4 + 1] * a1) * inv;
        v.z = (acc[e4][2] * a0 + base[e4 * 16 + g * 4 + 2] * a1) * inv;
        v.w = (acc[e4][3] * a0 + base[e4 * 16 + g * 4 + 3] * a1) * inv;
        *reinterpret_cast<float4*>(op + e4 * 16 + g * 4) = v;
      }
    }
  };

  // fused 17-round stream: rounds 0..RL-1 on tile lo, rest on tile hi
  constexpr int NRO = 17;
  loadq(QbL);
  issue(0);
  commit(0);
  __syncthreads();

  int cur = 0;
  for (int rd = 0; rd < NRO; ++rd) {
    const bool pre = (rd + 1 < NRO);
    if (pre) {
      const int nrd = rd + 1;
      const int nstr = (nrd < RL) ? nrd : nrd - RL;
      issue(nstr * 128);
    }
    const bool lo = (rd < RL);
    round(lo ? QbL : QbH, lo ? rd : rd - RL, cur);
    if (rd == RL - 1) {
      merge_store(QbL, cur);   // scratch overlays the just-consumed buffer
      #pragma unroll
      for (int e4 = 0; e4 < 4; ++e4) acc[e4] = zero4;
      mrun = NEGBIG;
      lrun = 0.f;
      loadq(QbH);
    }
    if (pre) commit(cur ^ 1);
    __syncthreads();
    cur ^= 1;
  }

  merge_store(QbH, cur ^ 1);
}

extern "C" void kernel_launch(void* const* d_in, const int* in_sizes, int n_in,
                              void* d_out, int out_size, void* d_ws, size_t ws_size,
                              hipStream_t stream) {
  const float* Q = (const float*)d_in[0];
  const float* K = (const float*)d_in[1];
  const float* V = (const float*)d_in[2];
  float* O = (float*)d_out;
  unsigned short* Kb = (unsigned short*)d_ws;
  unsigned short* Vt = (unsigned short*)((char*)d_ws + (size_t)Bc * Lc * Hc * Ec * 2);
  prep<<<dim3(3072), dim3(256), 0, stream>>>(K, V, (uint4*)Kb, Vt);
  dim3 grid(Bc * Hc * 16);   // 16 pairs x 32 bh; pair-major for XCD locality
  attn_fwd<<<grid, dim3(512), 0, stream>>>(Q, Kb, Vt, O);
}

// Round 20
// 48.979 us; speedup vs baseline: 1.5119x; 1.0112x over previous
//
#include <hip/hip_runtime.h>
#include <hip/hip_bf16.h>

typedef __attribute__((ext_vector_type(8))) short short8;
typedef __attribute__((ext_vector_type(4))) float f32x4;
typedef __attribute__((ext_vector_type(2))) unsigned uint2v;

#define MFMA16(a, b, c) __builtin_amdgcn_mfma_f32_16x16x32_bf16((a), (b), (c), 0, 0, 0)

constexpr int Bc = 2, Lc = 2048, Hc = 16, Ec = 64;
constexpr float LOG2E = 1.4426950408889634f;
constexpr float SCALE2 = 0.125f * LOG2E;   // fold log2(e): scores in log2 units
constexpr float NEGBIG = -3.0e38f;

union SW { short8 s8; unsigned u[4]; float4 f4; };

__device__ __forceinline__ unsigned cvtpk(float lo, float hi) {
  unsigned r;
  asm("v_cvt_pk_bf16_f32 %0, %1, %2" : "=v"(r) : "v"(lo), "v"(hi));
  return r;
}
__device__ __forceinline__ float exp2v(float x) {
  float r;
  asm("v_exp_f32 %0, %1" : "=v"(r) : "v"(x));
  return r;
}
__device__ __forceinline__ void plswap32(unsigned& a, unsigned& b) {
  uint2v r = __builtin_amdgcn_permlane32_swap(a, b, false, false);
  a = r[0]; b = r[1];
}
__device__ __forceinline__ void plswap16(unsigned& a, unsigned& b) {
  uint2v r = __builtin_amdgcn_permlane16_swap(a, b, false, false);
  a = r[0]; b = r[1];
}
__device__ __forceinline__ float bflymax(float x) {
  unsigned a = __builtin_bit_cast(unsigned, x), b = a;
  plswap16(a, b);
  float y = fmaxf(__builtin_bit_cast(float, a), __builtin_bit_cast(float, b));
  a = __builtin_bit_cast(unsigned, y); b = a;
  plswap32(a, b);
  return fmaxf(__builtin_bit_cast(float, a), __builtin_bit_cast(float, b));
}

// Fused prepass: K fp32->bf16 (RNE); V -> chunk-major Vt[bh][s/16][e][16] bf16.
__global__ __launch_bounds__(256)
void prep(const float* __restrict__ K, const float* __restrict__ V,
          uint4* __restrict__ Kb, unsigned short* __restrict__ Vt) {
  const int bid = blockIdx.x;
  const int t = threadIdx.x;
  if (bid < 2048) {
    const int i = bid * 256 + t;
    const float4* s = reinterpret_cast<const float4*>(K) + (size_t)i * 2;
    float4 a = s[0], b = s[1];
    uint4 o;
    o.x = cvtpk(a.x, a.y); o.y = cvtpk(a.z, a.w);
    o.z = cvtpk(b.x, b.y); o.w = cvtpk(b.z, b.w);
    Kb[i] = o;
  } else {
    const int vw = (bid - 2048) * 4 + (t >> 6);   // bh*128 + chunk
    const int l = t & 63;                          // e
    const int bh = vw >> 7;
    const int s0 = (vw & 127) * 16;
    const float* vp = V + ((size_t)(bh >> 4) * Lc + s0) * (Hc * Ec) +
                      (bh & 15) * Ec + l;
    float va[16];
    #pragma unroll
    for (int j = 0; j < 16; ++j) va[j] = vp[j * (Hc * Ec)];
    uint4 o0, o1;
    o0.x = cvtpk(va[0], va[1]);   o0.y = cvtpk(va[2], va[3]);
    o0.z = cvtpk(va[4], va[5]);   o0.w = cvtpk(va[6], va[7]);
    o1.x = cvtpk(va[8], va[9]);   o1.y = cvtpk(va[10], va[11]);
    o1.z = cvtpk(va[12], va[13]); o1.w = cvtpk(va[14], va[15]);
    uint4* dst = reinterpret_cast<uint4*>(Vt + ((size_t)vw * 64 + l) * 16);
    dst[0] = o0;
    dst[1] = o1;
  }
}

__global__ __launch_bounds__(512, 2)
void attn_fwd(const float* __restrict__ Qg, const unsigned short* __restrict__ Kb,
              const unsigned short* __restrict__ Vt, float* __restrict__ Og) {
  // smem (shorts), NT=128 s-tile double-buffered:
  //  kt[b]: [128][64] bf16 at b*8192, K row s at prow=pi(s), idx ^ ((prow&7)<<3)
  //  vt[b]: [64 e][128 s] bf16 at 16384 + b*8192, chunk slot = (s>>3) ^ (e&7)
  // merge scratch overlays the RETIRED buffer.
  __shared__ __align__(16) short smem[32768];

  // XCD-locality decode: bid = pair*32 + bh -> all 16 pair-blocks of a bh
  // share bid mod 8 (same XCD L2); the 2 blocks/CU share the same bh.
  const int bid = blockIdx.x;
  const int pair = bid >> 5;
  const int bh = bid & 31;
  const int h = bh & (Hc - 1);
  const int b = bh >> 4;
  const int iLo = pair;
  const int QbL = iLo * 64;
  const int QbH = (31 - pair) * 64;
  const int RL = (iLo + 2) >> 1;              // lo-tile rounds; RL + RH = 17

  const int t = threadIdx.x;
  const int w = t >> 6;        // 0..7
  const int qsub = w & 3;      // q sub-block (16 rows)
  const int par = w >> 2;      // 64-s half of the 128-row tile
  const int l = t & 63;
  const int n = l & 15;
  const int g = l >> 4;
  const int sp4 = ((g & 1) << 3) | ((g >> 1) << 2);  // pi(g)*4

  const f32x4 zero4 = {0.f, 0.f, 0.f, 0.f};
  short8 onesv;
  #pragma unroll
  for (int j = 0; j < 8; ++j) onesv[j] = (short)0x3F80;  // bf16 1.0

  // Q fragments (B-operand: col=q=lane&15, k=e=(lane>>4)*8+j)
  short8 qf[2];
  auto loadq = [&](int Qb) {
    const int q = Qb + qsub * 16 + n;
    const float* qp = Qg + ((size_t)(b * Lc + q) * Hc + h) * Ec + g * 8;
    SW a0, a1, b0, b1, r0, r1;
    a0.f4 = reinterpret_cast<const float4*>(qp)[0];
    a1.f4 = reinterpret_cast<const float4*>(qp)[1];
    b0.f4 = reinterpret_cast<const float4*>(qp + 32)[0];
    b1.f4 = reinterpret_cast<const float4*>(qp + 32)[1];
    r0.u[0] = cvtpk(a0.f4.x * SCALE2, a0.f4.y * SCALE2);
    r0.u[1] = cvtpk(a0.f4.z * SCALE2, a0.f4.w * SCALE2);
    r0.u[2] = cvtpk(a1.f4.x * SCALE2, a1.f4.y * SCALE2);
    r0.u[3] = cvtpk(a1.f4.z * SCALE2, a1.f4.w * SCALE2);
    r1.u[0] = cvtpk(b0.f4.x * SCALE2, b0.f4.y * SCALE2);
    r1.u[1] = cvtpk(b0.f4.z * SCALE2, b0.f4.w * SCALE2);
    r1.u[2] = cvtpk(b1.f4.x * SCALE2, b1.f4.y * SCALE2);
    r1.u[3] = cvtpk(b1.f4.z * SCALE2, b1.f4.w * SCALE2);
    qf[0] = r0.s8;
    qf[1] = r1.s8;
  };

  // acc[e4][r] = O^T[e = e4*16 + g*4 + r][q = n]; per-lane scalar m,l
  f32x4 acc[4] = {zero4, zero4, zero4, zero4};
  float mrun = NEGBIG, lrun = 0.f;

  // staging: 512 threads stage 128 rows of K (pi-permuted) and V^T per round
  const int srow = t >> 2;                               // 0..127
  const int prow = (srow & ~12) | ((srow & 4) << 1) | ((srow & 8) >> 1);
  const int kc0 = (t & 3) * 16;                          // 16-col bf16 chunk
  const int ve = l, vs0 = w * 16;                        // V^T: e=lane, 16 s rows

  float4 kA, kB, vA, vB;   // 4 x dwordx4 bf16

  // Forced-async bf16 stage: volatile asm loads issue HERE (unsinkable).
  auto issue = [&](int r0) {
    unsigned koff = (unsigned)((((b * Lc + r0 + srow) * Hc + h) * Ec + kc0) * 2);
    unsigned voff = (unsigned)(((bh * 128 + ((r0 + vs0) >> 4)) * 64 + ve) * 32);
    asm volatile(
      "global_load_dwordx4 %[k0], %[ko], %[kb]\n\t"
      "global_load_dwordx4 %[k1], %[ko], %[kb] offset:16\n\t"
      "global_load_dwordx4 %[v0], %[vo], %[vb]\n\t"
      "global_load_dwordx4 %[v1], %[vo], %[vb] offset:16"
      : [k0]"=v"(kA), [k1]"=v"(kB), [v0]"=v"(vA), [v1]"=v"(vB)
      : [ko]"v"(koff), [vo]"v"(voff), [kb]"s"(Kb), [vb]"s"(Vt)
      : "memory");
  };
  auto commit = [&](int buf) {
    asm volatile("s_waitcnt vmcnt(2)" ::: "memory");
    __builtin_amdgcn_sched_barrier(0);
    short* kt = smem + buf * 8192;
    *reinterpret_cast<short8*>(&kt[(prow * 64 + kc0) ^ ((prow & 7) << 3)]) =
        *reinterpret_cast<short8*>(&kA);
    *reinterpret_cast<short8*>(&kt[(prow * 64 + kc0 + 8) ^ ((prow & 7) << 3)]) =
        *reinterpret_cast<short8*>(&kB);
    asm volatile("s_waitcnt vmcnt(0)" ::: "memory");
    __builtin_amdgcn_sched_barrier(0);
    short* vt = smem + 16384 + buf * 8192;
    const int ch0 = vs0 >> 3;
    *reinterpret_cast<short8*>(&vt[ve * 128 + (((ch0 + 0) ^ (ve & 7)) << 3)]) =
        *reinterpret_cast<short8*>(&vA);
    *reinterpret_cast<short8*>(&vt[ve * 128 + (((ch0 + 1) ^ (ve & 7)) << 3)]) =
        *reinterpret_cast<short8*>(&vB);
  };

  // one 64q x 128s round (this wave: 16 q x 64 s half), swapped operands
  auto round = [&](int Qb, int str, int curb) {
    const int sb = str * 128 + par * 64;
    const int qtop = Qb + qsub * 16;
    if (sb > qtop + 15) return;
    const short* ktb = smem + curb * 8192;
    const short* vtb = smem + 16384 + curb * 8192;

    // QK^T swapped: D[s][q], col = q = n; 4 cb blocks x k=64
    f32x4 sc[4] = {zero4, zero4, zero4, zero4};
    __builtin_amdgcn_s_setprio(1);   // T5: favor this wave while MFMA-dense
    #pragma unroll
    for (int kc = 0; kc < 2; ++kc) {
      #pragma unroll
      for (int cb = 0; cb < 4; ++cb) {
        const int row = par * 64 + cb * 16 + n;
        const int idx = (row * 64 + kc * 32 + g * 8) ^ ((n & 7) << 3);
        short8 kf = *reinterpret_cast<const short8*>(&ktb[idx]);
        sc[cb] = MFMA16(kf, qf[kc], sc[cb]);
      }
    }
    __builtin_amdgcn_s_setprio(0);

    const int qg = qtop + n;
    if (sb + 63 > qtop) {
      #pragma unroll
      for (int cb = 0; cb < 4; ++cb)
        #pragma unroll
        for (int r = 0; r < 4; ++r)
          if (sb + cb * 16 + sp4 + r > qg) sc[cb][r] = NEGBIG;
    }

    // row max: 15 lane-local fmax + VALU butterfly
    float m8 = fmaxf(fmaxf(fmaxf(sc[0][0], sc[0][1]), fmaxf(sc[0][2], sc[0][3])),
                     fmaxf(fmaxf(sc[1][0], sc[1][1]), fmaxf(sc[1][2], sc[1][3])));
    m8 = fmaxf(m8, fmaxf(fmaxf(fmaxf(sc[2][0], sc[2][1]), fmaxf(sc[2][2], sc[2][3])),
                         fmaxf(fmaxf(sc[3][0], sc[3][1]), fmaxf(sc[3][2], sc[3][3]))));
    m8 = bflymax(m8);

    // exact-identity rescale skip
    const bool resc = !__all(m8 <= mrun);
    if (resc) {
      const float mn = fmaxf(mrun, m8);
      const float afac = exp2v(mrun - mn);
      mrun = mn;
      lrun *= afac;
      #pragma unroll
      for (int e4 = 0; e4 < 4; ++e4)
        #pragma unroll
        for (int r = 0; r < 4; ++r) acc[e4][r] *= afac;
    }

    // P = exp2(S - m) -> packed bf16
    unsigned ua[4], ub[4];
    #pragma unroll
    for (int cb = 0; cb < 4; ++cb) {
      ua[cb] = cvtpk(exp2v(sc[cb][0] - mrun), exp2v(sc[cb][1] - mrun));
      ub[cb] = cvtpk(exp2v(sc[cb][2] - mrun), exp2v(sc[cb][3] - mrun));
    }

    // P C-frag -> B-frag: pure-VALU permlane32 swaps
    plswap32(ua[0], ua[1]);
    plswap32(ub[0], ub[1]);
    plswap32(ua[2], ua[3]);
    plswap32(ub[2], ub[3]);
    SW pw0, pw1;
    pw0.u[0] = ua[0]; pw0.u[1] = ub[0]; pw0.u[2] = ua[1]; pw0.u[3] = ub[1];
    pw1.u[0] = ua[2]; pw1.u[1] = ub[2]; pw1.u[2] = ua[3]; pw1.u[3] = ub[3];

    // PV swapped + row sums: 10-MFMA cluster
    __builtin_amdgcn_s_setprio(1);
    #pragma unroll
    for (int e4 = 0; e4 < 4; ++e4) {
      const int e = e4 * 16 + n;
      const int slot0 = (par * 8 + g) ^ (e & 7);
      const int slot1 = (par * 8 + 4 + g) ^ (e & 7);
      short8 vf0 = *reinterpret_cast<const short8*>(&vtb[e * 128 + (slot0 << 3)]);
      acc[e4] = MFMA16(vf0, pw0.s8, acc[e4]);
      short8 vf1 = *reinterpret_cast<const short8*>(&vtb[e * 128 + (slot1 << 3)]);
      acc[e4] = MFMA16(vf1, pw1.s8, acc[e4]);
    }
    f32x4 rs = MFMA16(onesv, pw0.s8, zero4);
    rs = MFMA16(onesv, pw1.s8, rs);
    __builtin_amdgcn_s_setprio(0);
    lrun += rs[0];
  };

  // merge parities via scratch overlaid on the retired buffer `curb`
  auto merge_store = [&](int Qb, int curb) {
    float* sA = reinterpret_cast<float*>(smem) + curb * 4096;         // rows 0..31
    float* sB = reinterpret_cast<float*>(smem) + 8192 + curb * 4096;  // rows 32..63 + m + l
    __syncthreads();
    const int row = qsub * 16 + n;
    if (par == 1) {
      float* base = (row < 32) ? (sA + row * 68) : (sB + (row - 32) * 68);
      #pragma unroll
      for (int e4 = 0; e4 < 4; ++e4)
        #pragma unroll
        for (int r = 0; r < 4; ++r) base[e4 * 16 + g * 4 + r] = acc[e4][r];
      if (g == 0) {
        sB[2176 + row] = mrun;
        sB[2240 + row] = lrun;
      }
    }
    __syncthreads();
    if (par == 0) {
      const float* base = (row < 32) ? (sA + row * 68) : (sB + (row - 32) * 68);
      const float m1 = sB[2176 + row];
      const float l1 = sB[2240 + row];
      const float mm = fmaxf(mrun, m1);
      const float a0 = exp2v(mrun - mm);
      const float a1 = exp2v(m1 - mm);
      const float inv = 1.0f / (lrun * a0 + l1 * a1);
      const int q = Qb + row;
      float* op = Og + ((size_t)(b * Lc + q) * Hc + h) * Ec;
      #pragma unroll
      for (int e4 = 0; e4 < 4; ++e4) {
        float4 v;
        v.x = (acc[e4][0] * a0 + base[e4 * 16 + g * 4 + 0] * a1) * inv;
        v.y = (acc[e4][1] * a0 + base[e4 * 16 + g * 4 + 1] * a1) * inv;
        v.z = (acc[e4][2] * a0 + base[e4 * 16 + g * 4 + 2] * a1) * inv;
        v.w = (acc[e4][3] * a0 + base[e4 * 16 + g * 4 + 3] * a1) * inv;
        *reinterpret_cast<float4*>(op + e4 * 16 + g * 4) = v;
      }
    }
  };

  // fused 17-round stream: rounds 0..RL-1 on tile lo, rest on tile hi
  constexpr int NRO = 17;
  loadq(QbL);
  issue(0);
  commit(0);
  __syncthreads();

  int cur = 0;
  for (int rd = 0; rd < NRO; ++rd) {
    const bool pre = (rd + 1 < NRO);
    if (pre) {
      const int nrd = rd + 1;
      const int nstr = (nrd < RL) ? nrd : nrd - RL;
      issue(nstr * 128);
    }
    const bool lo = (rd < RL);
    round(lo ? QbL : QbH, lo ? rd : rd - RL, cur);
    if (rd == RL - 1) {
      merge_store(QbL, cur);   // scratch overlays the just-consumed buffer
      #pragma unroll
      for (int e4 = 0; e4 < 4; ++e4) acc[e4] = zero4;
      mrun = NEGBIG;
      lrun = 0.f;
      loadq(QbH);
    }
    if (pre) commit(cur ^ 1);
    __syncthreads();
    cur ^= 1;
  }

  merge_store(QbH, cur ^ 1);
}

extern "C" void kernel_launch(void* const* d_in, const int* in_sizes, int n_in,
                              void* d_out, int out_size, void* d_ws, size_t ws_size,
                              hipStream_t stream) {
  const float* Q = (const float*)d_in[0];
  const float* K = (const float*)d_in[1];
  const float* V = (const float*)d_in[2];
  float* O = (float*)d_out;
  unsigned short* Kb = (unsigned short*)d_ws;
  unsigned short* Vt = (unsigned short*)((char*)d_ws + (size_t)Bc * Lc * Hc * Ec * 2);
  prep<<<dim3(3072), dim3(256), 0, stream>>>(K, V, (uint4*)Kb, Vt);
  dim3 grid(Bc * Hc * 16);   // 16 pairs x 32 bh; pair-major for XCD locality
  attn_fwd<<<grid, dim3(512), 0, stream>>>(Q, Kb, Vt, O);
}